// Round 6
// baseline (1410.535 us; speedup 1.0000x reference)
//
#include <hip/hip_runtime.h>
#include <hip/hip_bf16.h>

typedef _Float16 v8h __attribute__((ext_vector_type(8)));
typedef _Float16 v4h __attribute__((ext_vector_type(4)));
typedef float    v4f __attribute__((ext_vector_type(4)));

#define NTOT  16384
#define NN    70
#define EE    3
#define SS    10
#define STEPS 5
#define NB    4
#define NPAIR (NB*NN)        // 280 active of 320
#define TPB   320            // 5 waves; every wave owns one M-tile
#define NBLK  (NTOT/NB)      // 4096
#define JTOT  210            // K dim
#define KP    224            // K padded (7 tiles of 32)
#define NCOLR 40             // real cols (4 graphs * 10 states)
#define NCOLP 48             // padded to 3 N-tiles of 16
#define USTR  232            // U_T col stride, fp16 (464 B = 116 dwords, 29 odd -> bank-friendly)
#define CSTRH 88             // Csm col stride, fp16 (176 B, 16B-aligned)

// weight offsets (floats) inside g_w
#define OFF_WIN 0
#define OFF_BIN 300
#define OFF_WR  330
#define OFF_BR  530
#define OFF_WZ  540
#define OFF_BZ  740
#define OFF_WH  750
#define OFF_BH  950
#define OFF_WO1 960
#define OFF_BO1 1070
#define OFF_WO2 1080
#define OFF_BO2 1090
#define NWTOT   1091

__device__ float g_w[NWTOT + 1];
__device__ int   g_flag;

__device__ __forceinline__ float fast_sigmoid(float x) {
    return __builtin_amdgcn_rcpf(1.0f + __expf(-x));
}
__device__ __forceinline__ float fast_tanh(float x) {
    float ax = fabsf(x);
    float e  = __expf(-2.0f * ax);
    float t  = (1.0f - e) * __builtin_amdgcn_rcpf(1.0f + e);
    return copysignf(t, x);
}

struct __align__(16) Smem {
    union {
        _Float16 Astage[NN*KP];            // 31360 B (A fp16, read once into frags)
        struct {
            _Float16 U[NCOLP*USTR];        // 22272 B: U_T[col][k]
            _Float16 C[NCOLP*CSTRH];       // 8448 B:  Csm[col][node], fp16
        } s;
    } u;
};
// sizeof = 31360 B -> 4 blocks/CU (with launch_bounds cap)

// ---- prep: probe dtype once, convert all weights to fp32 in g_w ----
__global__ void prep_kernel(const void* annv,
    const void* s0, const void* s1, const void* s2, const void* s3,
    const void* s4, const void* s5, const void* s6, const void* s7,
    const void* s8, const void* s9, const void* s10, const void* s11)
{
    __shared__ int sflag;
    if (threadIdx.x == 0) {
        const unsigned short* u = (const unsigned short*)annv;
        int good = 0;
        for (int k = 0; k < 128; ++k) {
            unsigned short bb = u[k];
            int ex = (bb >> 7) & 0xFF;
            if (bb == 0 || (ex >= 101 && ex <= 131)) ++good;
        }
        sflag = (good >= 112) ? 1 : 0;
        g_flag = sflag;
    }
    __syncthreads();
    const int f = sflag;
    const void* srcs[12] = {s0,s1,s2,s3,s4,s5,s6,s7,s8,s9,s10,s11};
    const int offs[12] = {OFF_WIN,OFF_BIN,OFF_WR,OFF_BR,OFF_WZ,OFF_BZ,
                          OFF_WH,OFF_BH,OFF_WO1,OFF_BO1,OFF_WO2,OFF_BO2};
    const int cnts[12] = {300,30,200,10,200,10,200,10,110,10,10,1};
    for (int a = 0; a < 12; ++a)
        for (int k = threadIdx.x; k < cnts[a]; k += blockDim.x)
            g_w[offs[a] + k] = f ? (float)((const __hip_bfloat16*)srcs[a])[k]
                                 : ((const float*)srcs[a])[k];
}

template<typename T>
__device__ __forceinline__ void run_impl(const void* annv, const void* Av,
                                         void* outv, Smem& sm)
{
    const T* ann_g = (const T*)annv;
    const T* A_g   = (const T*)Av;
    T* out_g       = (T*)outv;
    const int tid  = threadIdx.x;
    const int blk  = blockIdx.x;
    const int w    = tid >> 6;      // wave id 0..4 == M-tile id
    const int lane = tid & 63;
    const float* __restrict__ gw = g_w;

    // ---- stage A into LDS as fp16 (k-pad zeroed): A[n][j] -> Astage[n*KP + j]
    for (int idx = tid; idx < NN*KP; idx += TPB) {
        const int n2 = idx / KP;
        const int j  = idx - n2*KP;
        sm.u.Astage[idx] = (j < JTOT) ? (_Float16)(float)A_g[n2*JTOT + j] : (_Float16)0.f;
    }
    __syncthreads();

    // ---- preload A fragments (step-invariant): wave w owns M-tile w
    // A-frag (16x16x32): lane holds A[m=lane&15][k=(lane>>4)*8 + j], j=0..7
    v8h a_frag[7];
    {
        const int m  = w*16 + (lane & 15);
        const int mr = (m < NN) ? m : 0;
        const int q  = lane >> 4;
        const _Float16* As = &sm.u.Astage[mr*KP + q*8];
        const v8h zero8 = {0,0,0,0,0,0,0,0};
        #pragma unroll
        for (int kt = 0; kt < 7; ++kt)
            a_frag[kt] = (m < NN) ? *(const v8h*)(As + kt*32) : zero8;
    }
    __syncthreads();   // frags in regs before U/C overwrite the union

    // ---- zero the whole U+C region once (covers pad cols + k-pads; real
    //      parts get overwritten each step, pads stay zero)
    {
        int* z = (int*)&sm.u.s;
        const int ndw = (int)(sizeof(sm.u.s) / 4);
        for (int idx = tid; idx < ndw; idx += TPB) z[idx] = 0;
    }

    const int g    = tid / NN;            // graph 0..3 (4 for tail threads)
    const int n    = tid - g*NN;          // node 0..69
    const bool act = (tid < NPAIR);
    const int gl   = act ? g : 0;         // clamp for safe LDS addressing
    const int b    = blk*NB + gl;

    float ann = 0.f;
    float pr[SS];
    #pragma unroll
    for (int s = 0; s < SS; ++s) pr[s] = 0.f;
    if (act) { ann = (float)ann_g[b*NN + n]; pr[0] = ann; }

    #pragma unroll 1
    for (int step = 0; step < STEPS; ++step) {
        // ---- U-build: thread (g,n) writes ins rows j=e*70+n for its graph
        {
            _Float16* uw = &sm.u.s.U[(gl*SS)*USTR + n];
            #pragma unroll
            for (int e = 0; e < EE; ++e)
                #pragma unroll
                for (int s = 0; s < SS; ++s) {
                    float uv = gw[OFF_BIN + e*SS + s];
                    #pragma unroll
                    for (int t = 0; t < SS; ++t)
                        uv += gw[OFF_WIN + e*100 + s*SS + t] * pr[t];
                    if (act) uw[s*USTR + e*NN] = (_Float16)uv;
                }
        }
        __syncthreads();   // U complete (incl. zero pads) before B-frag reads

        // ---- MFMA: wave w -> M-tile w, 3 N-tiles, 7 K-tiles
        {
            const int c = lane & 15, q = lane >> 4;
            #pragma unroll
            for (int nt = 0; nt < 3; ++nt) {
                v4f acc = {0.f, 0.f, 0.f, 0.f};
                const _Float16* Ub = &sm.u.s.U[(nt*16 + c)*USTR + q*8];
                #pragma unroll
                for (int kt = 0; kt < 7; ++kt) {
                    v8h bfrag = *(const v8h*)(Ub + kt*32);
                    acc = __builtin_amdgcn_mfma_f32_16x16x32_f16(a_frag[kt], bfrag, acc, 0, 0, 0);
                }
                // C-frag: lane holds C[m0..m0+3][col]; pack fp16, write b64
                v4h ch = { (_Float16)acc[0], (_Float16)acc[1],
                           (_Float16)acc[2], (_Float16)acc[3] };
                _Float16* cwp = &sm.u.s.C[(nt*16 + c)*CSTRH + w*16 + q*4];
                *(v4h*)cwp = ch;
            }
        }
        __syncthreads();   // C complete before gate reads

        // ---- gates
        {
            float ai[SS];
            const _Float16* cr = &sm.u.s.C[(gl*SS)*CSTRH + n];
            #pragma unroll
            for (int s = 0; s < SS; ++s) ai[s] = (float)cr[s*CSTRH];

            float rp[SS], hh[SS];
            #pragma unroll
            for (int s = 0; s < SS; ++s) {
                float acc = gw[OFF_BR+s];
                #pragma unroll
                for (int d = 0; d < SS; ++d) acc += ai[d]*gw[OFF_WR + s*2*SS + d];
                #pragma unroll
                for (int d = 0; d < SS; ++d) acc += pr[d]*gw[OFF_WR + s*2*SS + SS + d];
                rp[s] = fast_sigmoid(acc) * pr[s];   // r * prop
            }
            #pragma unroll
            for (int s = 0; s < SS; ++s) {
                float acc = gw[OFF_BH+s];
                #pragma unroll
                for (int d = 0; d < SS; ++d) acc += ai[d]*gw[OFF_WH + s*2*SS + d];
                #pragma unroll
                for (int d = 0; d < SS; ++d) acc += rp[d]*gw[OFF_WH + s*2*SS + SS + d];
                hh[s] = fast_tanh(acc);
            }
            #pragma unroll
            for (int s = 0; s < SS; ++s) {
                float acc = gw[OFF_BZ+s];
                #pragma unroll
                for (int d = 0; d < SS; ++d) acc += ai[d]*gw[OFF_WZ + s*2*SS + d];
                #pragma unroll
                for (int d = 0; d < SS; ++d) acc += pr[d]*gw[OFF_WZ + s*2*SS + SS + d];
                const float z = fast_sigmoid(acc);
                pr[s] += z*(hh[s]-pr[s]);
            }
        }
        __syncthreads();   // gates' C reads done before next step's writes
    }

    // ---- epilogue: out = tanh([prop, ann] @ Wo1^T + bo1) @ Wo2^T + bo2
    if (act) {
        float o = gw[OFF_BO2];
        #pragma unroll
        for (int s = 0; s < SS; ++s) {
            float acc = gw[OFF_BO1+s] + ann*gw[OFF_WO1 + s*(SS+1) + SS];
            #pragma unroll
            for (int d = 0; d < SS; ++d) acc += pr[d]*gw[OFF_WO1 + s*(SS+1) + d];
            o += fast_tanh(acc) * gw[OFF_WO2 + s];
        }
        out_g[b*NN + n] = (T)o;
    }
}

__global__ __launch_bounds__(TPB, 5)   // 5 waves/EU -> 4 blocks/CU, VGPR cap 102
void ggnn_kernel(const void* annv, const void* Av, void* outv)
{
    __shared__ Smem sm;
    if (g_flag)
        run_impl<__hip_bfloat16>(annv, Av, outv, sm);
    else
        run_impl<float>(annv, Av, outv, sm);
}

extern "C" void kernel_launch(void* const* d_in, const int* in_sizes, int n_in,
                              void* d_out, int out_size, void* d_ws, size_t ws_size,
                              hipStream_t stream) {
    (void)in_sizes; (void)n_in; (void)out_size; (void)d_ws; (void)ws_size;
    hipLaunchKernelGGL(prep_kernel, dim3(1), dim3(256), 0, stream,
        d_in[0], d_in[2], d_in[3], d_in[4], d_in[5], d_in[6], d_in[7],
        d_in[8], d_in[9], d_in[10], d_in[11], d_in[12], d_in[13]);
    hipLaunchKernelGGL(ggnn_kernel, dim3(NBLK), dim3(TPB), 0, stream,
        d_in[0], d_in[1], d_out);
}

// Round 7
// 982.452 us; speedup vs baseline: 1.4357x; 1.4357x over previous
//
#include <hip/hip_runtime.h>
#include <hip/hip_bf16.h>

typedef _Float16 v8h __attribute__((ext_vector_type(8)));
typedef _Float16 v4h __attribute__((ext_vector_type(4)));
typedef float    v4f __attribute__((ext_vector_type(4)));

#define NTOT  16384
#define NN    70
#define EE    3
#define SS    10
#define STEPS 5
#define NB    4
#define NPAIR (NB*NN)        // 280 active of 320
#define TPB   320            // 5 waves; every wave owns one M-tile
#define NBLK  (NTOT/NB)      // 4096
#define JTOT  210            // K dim
#define KP    224            // K padded (7 tiles of 32)
#define NCOLR 40             // real cols (4 graphs * 10 states)
#define NCOLP 48             // padded to 3 N-tiles of 16
#define USTR  232            // U_T col stride, fp16 (464 B = 116 dwords, 29 odd -> bank-friendly)
#define CSTRH 88             // Csm col stride, fp16 (176 B, 16B-aligned)

// weight offsets (floats) inside g_w
#define OFF_WIN 0
#define OFF_BIN 300
#define OFF_WR  330
#define OFF_BR  530
#define OFF_WZ  540
#define OFF_BZ  740
#define OFF_WH  750
#define OFF_BH  950
#define OFF_WO1 960
#define OFF_BO1 1070
#define OFF_WO2 1080
#define OFF_BO2 1090
#define NWTOT   1091

__device__ float g_w[NWTOT + 1];
__device__ int   g_flag;

__device__ __forceinline__ float fast_sigmoid(float x) {
    return __builtin_amdgcn_rcpf(1.0f + __expf(-x));
}
__device__ __forceinline__ float fast_tanh(float x) {
    float ax = fabsf(x);
    float e  = __expf(-2.0f * ax);
    float t  = (1.0f - e) * __builtin_amdgcn_rcpf(1.0f + e);
    return copysignf(t, x);
}

struct __align__(16) Smem {
    union {
        _Float16 Astage[NN*KP];            // 31360 B (A fp16, read once into frags)
        struct {
            _Float16 U[NCOLP*USTR];        // 22272 B: U_T[col][k]
            _Float16 C[NCOLP*CSTRH];       // 8448 B:  Csm[col][node], fp16
        } s;
    } u;
};
// sizeof = 31360 B -> 4+ blocks/CU by LDS

// ---- prep: probe dtype once, convert all weights to fp32 in g_w ----
__global__ void prep_kernel(const void* annv,
    const void* s0, const void* s1, const void* s2, const void* s3,
    const void* s4, const void* s5, const void* s6, const void* s7,
    const void* s8, const void* s9, const void* s10, const void* s11)
{
    __shared__ int sflag;
    if (threadIdx.x == 0) {
        const unsigned short* u = (const unsigned short*)annv;
        int good = 0;
        for (int k = 0; k < 128; ++k) {
            unsigned short bb = u[k];
            int ex = (bb >> 7) & 0xFF;
            if (bb == 0 || (ex >= 101 && ex <= 131)) ++good;
        }
        sflag = (good >= 112) ? 1 : 0;
        g_flag = sflag;
    }
    __syncthreads();
    const int f = sflag;
    const void* srcs[12] = {s0,s1,s2,s3,s4,s5,s6,s7,s8,s9,s10,s11};
    const int offs[12] = {OFF_WIN,OFF_BIN,OFF_WR,OFF_BR,OFF_WZ,OFF_BZ,
                          OFF_WH,OFF_BH,OFF_WO1,OFF_BO1,OFF_WO2,OFF_BO2};
    const int cnts[12] = {300,30,200,10,200,10,200,10,110,10,10,1};
    for (int a = 0; a < 12; ++a)
        for (int k = threadIdx.x; k < cnts[a]; k += blockDim.x)
            g_w[offs[a] + k] = f ? (float)((const __hip_bfloat16*)srcs[a])[k]
                                 : ((const float*)srcs[a])[k];
}

template<typename T>
__device__ __forceinline__ void run_impl(const void* annv, const void* Av,
                                         void* outv, Smem& sm)
{
    const T* ann_g = (const T*)annv;
    const T* A_g   = (const T*)Av;
    T* out_g       = (T*)outv;
    const int tid  = threadIdx.x;
    const int blk  = blockIdx.x;
    const int w    = tid >> 6;      // wave id 0..4 == M-tile id
    const int lane = tid & 63;
    const float* __restrict__ gw = g_w;

    // ---- stage A into LDS as fp16 (k-pad zeroed): A[n][j] -> Astage[n*KP + j]
    for (int idx = tid; idx < NN*KP; idx += TPB) {
        const int n2 = idx / KP;
        const int j  = idx - n2*KP;
        sm.u.Astage[idx] = (j < JTOT) ? (_Float16)(float)A_g[n2*JTOT + j] : (_Float16)0.f;
    }
    __syncthreads();

    // ---- preload A fragments (step-invariant): wave w owns M-tile w
    // A-frag (16x16x32): lane holds A[m=lane&15][k=(lane>>4)*8 + j], j=0..7
    v8h a_frag[7];
    {
        const int m  = w*16 + (lane & 15);
        const int mr = (m < NN) ? m : 0;
        const int q  = lane >> 4;
        const _Float16* As = &sm.u.Astage[mr*KP + q*8];
        const v8h zero8 = {0,0,0,0,0,0,0,0};
        #pragma unroll
        for (int kt = 0; kt < 7; ++kt)
            a_frag[kt] = (m < NN) ? *(const v8h*)(As + kt*32) : zero8;
    }
    __syncthreads();   // frags in regs before U/C overwrite the union

    // ---- zero the whole U+C region once (covers pad cols + k-pads; real
    //      parts get overwritten each step, pads stay zero)
    {
        int* z = (int*)&sm.u.s;
        const int ndw = (int)(sizeof(sm.u.s) / 4);
        for (int idx = tid; idx < ndw; idx += TPB) z[idx] = 0;
    }

    const int g    = tid / NN;            // graph 0..3 (4 for tail threads)
    const int n    = tid - g*NN;          // node 0..69
    const bool act = (tid < NPAIR);
    const int gl   = act ? g : 0;         // clamp for safe LDS addressing
    const int b    = blk*NB + gl;

    float ann = 0.f;
    float pr[SS];
    #pragma unroll
    for (int s = 0; s < SS; ++s) pr[s] = 0.f;
    if (act) { ann = (float)ann_g[b*NN + n]; pr[0] = ann; }

    #pragma unroll 1
    for (int step = 0; step < STEPS; ++step) {
        // ---- U-build: thread (g,n) writes ins rows j=e*70+n for its graph
        {
            _Float16* uw = &sm.u.s.U[(gl*SS)*USTR + n];
            #pragma unroll
            for (int e = 0; e < EE; ++e)
                #pragma unroll
                for (int s = 0; s < SS; ++s) {
                    float uv = gw[OFF_BIN + e*SS + s];
                    #pragma unroll
                    for (int t = 0; t < SS; ++t)
                        uv += gw[OFF_WIN + e*100 + s*SS + t] * pr[t];
                    if (act) uw[s*USTR + e*NN] = (_Float16)uv;
                }
        }
        __syncthreads();   // U complete (incl. zero pads) before B-frag reads

        // ---- MFMA: wave w -> M-tile w, 3 N-tiles, 7 K-tiles
        {
            const int c = lane & 15, q = lane >> 4;
            #pragma unroll
            for (int nt = 0; nt < 3; ++nt) {
                v4f acc = {0.f, 0.f, 0.f, 0.f};
                const _Float16* Ub = &sm.u.s.U[(nt*16 + c)*USTR + q*8];
                #pragma unroll
                for (int kt = 0; kt < 7; ++kt) {
                    v8h bfrag = *(const v8h*)(Ub + kt*32);
                    acc = __builtin_amdgcn_mfma_f32_16x16x32_f16(a_frag[kt], bfrag, acc, 0, 0, 0);
                }
                // C-frag: lane holds C[m0..m0+3][col]; pack fp16, write b64
                v4h ch = { (_Float16)acc[0], (_Float16)acc[1],
                           (_Float16)acc[2], (_Float16)acc[3] };
                _Float16* cwp = &sm.u.s.C[(nt*16 + c)*CSTRH + w*16 + q*4];
                *(v4h*)cwp = ch;
            }
        }
        __syncthreads();   // C complete before gate reads

        // ---- gates
        {
            float ai[SS];
            const _Float16* cr = &sm.u.s.C[(gl*SS)*CSTRH + n];
            #pragma unroll
            for (int s = 0; s < SS; ++s) ai[s] = (float)cr[s*CSTRH];

            float rp[SS], hh[SS];
            #pragma unroll
            for (int s = 0; s < SS; ++s) {
                float acc = gw[OFF_BR+s];
                #pragma unroll
                for (int d = 0; d < SS; ++d) acc += ai[d]*gw[OFF_WR + s*2*SS + d];
                #pragma unroll
                for (int d = 0; d < SS; ++d) acc += pr[d]*gw[OFF_WR + s*2*SS + SS + d];
                rp[s] = fast_sigmoid(acc) * pr[s];   // r * prop
            }
            #pragma unroll
            for (int s = 0; s < SS; ++s) {
                float acc = gw[OFF_BH+s];
                #pragma unroll
                for (int d = 0; d < SS; ++d) acc += ai[d]*gw[OFF_WH + s*2*SS + d];
                #pragma unroll
                for (int d = 0; d < SS; ++d) acc += rp[d]*gw[OFF_WH + s*2*SS + SS + d];
                hh[s] = fast_tanh(acc);
            }
            #pragma unroll
            for (int s = 0; s < SS; ++s) {
                float acc = gw[OFF_BZ+s];
                #pragma unroll
                for (int d = 0; d < SS; ++d) acc += ai[d]*gw[OFF_WZ + s*2*SS + d];
                #pragma unroll
                for (int d = 0; d < SS; ++d) acc += pr[d]*gw[OFF_WZ + s*2*SS + SS + d];
                const float z = fast_sigmoid(acc);
                pr[s] += z*(hh[s]-pr[s]);
            }
        }
        __syncthreads();   // gates' C reads done before next step's writes
    }

    // ---- epilogue: out = tanh([prop, ann] @ Wo1^T + bo1) @ Wo2^T + bo2
    if (act) {
        float o = gw[OFF_BO2];
        #pragma unroll
        for (int s = 0; s < SS; ++s) {
            float acc = gw[OFF_BO1+s] + ann*gw[OFF_WO1 + s*(SS+1) + SS];
            #pragma unroll
            for (int d = 0; d < SS; ++d) acc += pr[d]*gw[OFF_WO1 + s*(SS+1) + d];
            o += fast_tanh(acc) * gw[OFF_WO2 + s];
        }
        out_g[b*NN + n] = (T)o;
    }
}

// min-waves=4 (NOT 5): backend rounds 5 up to the 8-waves/EU occupancy step ->
// 64-VGPR budget -> spills (R1/R3/R5/R6 all show VGPR=48 + scratch traffic).
// min-waves=4 -> 128-VGPR budget, live set ~90 fits, and 4 blocks/CU still
// achievable in HW (5 waves/SIMD x ~100 VGPR = 500 <= 512).
__global__ __launch_bounds__(TPB, 4)
void ggnn_kernel(const void* annv, const void* Av, void* outv)
{
    __shared__ Smem sm;
    if (g_flag)
        run_impl<__hip_bfloat16>(annv, Av, outv, sm);
    else
        run_impl<float>(annv, Av, outv, sm);
}

extern "C" void kernel_launch(void* const* d_in, const int* in_sizes, int n_in,
                              void* d_out, int out_size, void* d_ws, size_t ws_size,
                              hipStream_t stream) {
    (void)in_sizes; (void)n_in; (void)out_size; (void)d_ws; (void)ws_size;
    hipLaunchKernelGGL(prep_kernel, dim3(1), dim3(256), 0, stream,
        d_in[0], d_in[2], d_in[3], d_in[4], d_in[5], d_in[6], d_in[7],
        d_in[8], d_in[9], d_in[10], d_in[11], d_in[12], d_in[13]);
    hipLaunchKernelGGL(ggnn_kernel, dim3(NBLK), dim3(TPB), 0, stream,
        d_in[0], d_in[1], d_out);
}

// Round 8
// 613.427 us; speedup vs baseline: 2.2994x; 1.6016x over previous
//
#include <hip/hip_runtime.h>
#include <hip/hip_bf16.h>

typedef _Float16 v8h __attribute__((ext_vector_type(8)));
typedef _Float16 v4h __attribute__((ext_vector_type(4)));
typedef float    v4f __attribute__((ext_vector_type(4)));

#define NTOT  16384
#define NN    70
#define EE    3
#define SS    10
#define STEPS 5
#define NB    4
#define NPAIR (NB*NN)        // 280 active of 320
#define TPB   320            // 5 waves; every wave owns one M-tile
#define NBLK  (NTOT/NB)      // 4096
#define JTOT  210            // K dim
#define KP    224            // K padded (7 tiles of 32)
#define NCOLP 48             // cols padded to 3 N-tiles of 16
#define USTR  232            // U_T col stride, fp16
#define CSTRH 88             // Csm col stride, fp16

// ---- padded weight layout (floats) in g_w / lw ----
// PWIN: 30 rows x 12: [W_in[e][s][0..9], b_in[e][s], 0]
// PWR/PWZ/PWH: 10 rows x 20
// PBR/PBZ/PBH: 10 each (scalar)
// PWO1: 10 rows x 12: [Wo1[s][0..9], Wo1[s][10], bo1[s]]
// PWO2: 10, PBO2: 1
#define PWIN 0
#define PWR  360
#define PWZ  560
#define PWH  760
#define PBR  960
#define PBZ  970
#define PBH  980
#define PWO1 992
#define PWO2 1112
#define PBO2 1122
#define NWP  1128

__device__ float g_w[NWP];
__device__ int   g_flag;

__device__ __forceinline__ float fast_sigmoid(float x) {
    return __builtin_amdgcn_rcpf(1.0f + __expf(-x));
}
__device__ __forceinline__ float fast_tanh(float x) {
    float ax = fabsf(x);
    float e  = __expf(-2.0f * ax);
    float t  = (1.0f - e) * __builtin_amdgcn_rcpf(1.0f + e);
    return copysignf(t, x);
}

struct __align__(16) Smem {
    float lw[NWP];                         // 4512 B, all weights (padded layout)
    union {
        _Float16 Astage[NN*KP];            // 31360 B
        struct {
            _Float16 U[NCOLP*USTR];        // 22272 B: U_T[col][k]
            _Float16 C[NCOLP*CSTRH];       // 8448 B:  Csm[col][node], fp16
        } s;
    } u;
};
// sizeof = 35872 B -> 4 blocks/CU by LDS

// ---- prep: probe dtype once, build padded fp32 weight image in g_w ----
__global__ void prep_kernel(const void* annv,
    const void* winv, const void* binv, const void* wrv, const void* brv,
    const void* wzv, const void* bzv, const void* whv, const void* bhv,
    const void* wo1v, const void* bo1v, const void* wo2v, const void* bo2v)
{
    __shared__ int sflag;
    if (threadIdx.x == 0) {
        const unsigned short* u = (const unsigned short*)annv;
        int good = 0;
        for (int k = 0; k < 128; ++k) {
            unsigned short bb = u[k];
            int ex = (bb >> 7) & 0xFF;
            if (bb == 0 || (ex >= 101 && ex <= 131)) ++good;
        }
        sflag = (good >= 112) ? 1 : 0;
        g_flag = sflag;
    }
    __syncthreads();
    const int f = sflag;
    #define RD(p, i) (f ? (float)((const __hip_bfloat16*)(p))[i] : ((const float*)(p))[i])
    const int tid = threadIdx.x;
    // WIN rows (padded 12, bias at col 10)
    for (int idx = tid; idx < 360; idx += blockDim.x) {
        const int r = idx / 12, c = idx - r*12;   // r = e*10+s
        float v = 0.f;
        if (c < 10)       v = RD(winv, r*10 + c);
        else if (c == 10) v = RD(binv, r);
        g_w[PWIN + idx] = v;
    }
    // gate weight rows (20 wide, already 16B-stride)
    for (int idx = tid; idx < 200; idx += blockDim.x) {
        g_w[PWR + idx] = RD(wrv, idx);
        g_w[PWZ + idx] = RD(wzv, idx);
        g_w[PWH + idx] = RD(whv, idx);
    }
    for (int idx = tid; idx < 10; idx += blockDim.x) {
        g_w[PBR + idx] = RD(brv, idx);
        g_w[PBZ + idx] = RD(bzv, idx);
        g_w[PBH + idx] = RD(bhv, idx);
        g_w[PWO2 + idx] = RD(wo2v, idx);
    }
    // WO1 rows (padded 12: [w0..w9, ann_coef, bo1])
    for (int idx = tid; idx < 120; idx += blockDim.x) {
        const int s = idx / 12, c = idx - s*12;
        float v;
        if (c < 11)      v = RD(wo1v, s*11 + c);
        else             v = RD(bo1v, s);
        g_w[PWO1 + idx] = v;
    }
    if (tid == 0) {
        g_w[PBO2] = RD(bo2v, 0);
        for (int k = PBO2+1; k < NWP; ++k) g_w[k] = 0.f;
        for (int k = PBR+10; k < PBZ; ++k) g_w[k] = 0.f;
        for (int k = PBZ+10; k < PBH; ++k) g_w[k] = 0.f;
        for (int k = PBH+10; k < PWO1; ++k) g_w[k] = 0.f;
    }
    #undef RD
}

template<typename T>
__device__ __forceinline__ void run_impl(const void* annv, const void* Av,
                                         void* outv, Smem& sm)
{
    const T* ann_g = (const T*)annv;
    const T* A_g   = (const T*)Av;
    T* out_g       = (T*)outv;
    const int tid  = threadIdx.x;
    const int blk  = blockIdx.x;
    const int w    = tid >> 6;      // wave id 0..4 == M-tile id
    const int lane = tid & 63;
    const float* lw = sm.lw;
    const v4f*   LW4 = (const v4f*)sm.lw;

    // ---- copy padded weights into LDS (broadcast-read source for all phases)
    for (int i = tid; i < NWP; i += TPB) sm.lw[i] = g_w[i];

    // ---- stage A into LDS as fp16 (k-pad zeroed): A[n][j] -> Astage[n*KP + j]
    for (int idx = tid; idx < NN*KP; idx += TPB) {
        const int n2 = idx / KP;
        const int j  = idx - n2*KP;
        sm.u.Astage[idx] = (j < JTOT) ? (_Float16)(float)A_g[n2*JTOT + j] : (_Float16)0.f;
    }
    __syncthreads();

    // ---- preload A fragments (step-invariant): wave w owns M-tile w
    v8h a_frag[7];
    {
        const int m  = w*16 + (lane & 15);
        const int mr = (m < NN) ? m : 0;
        const int q  = lane >> 4;
        const _Float16* As = &sm.u.Astage[mr*KP + q*8];
        const v8h zero8 = {0,0,0,0,0,0,0,0};
        #pragma unroll
        for (int kt = 0; kt < 7; ++kt)
            a_frag[kt] = (m < NN) ? *(const v8h*)(As + kt*32) : zero8;
    }
    __syncthreads();   // frags in regs before U/C overwrite the union

    // ---- zero the whole U+C region once (pads stay zero thereafter)
    {
        int* z = (int*)&sm.u.s;
        const int ndw = (int)(sizeof(sm.u.s) / 4);
        for (int idx = tid; idx < ndw; idx += TPB) z[idx] = 0;
    }

    const int g    = tid / NN;            // graph 0..3 (4 for tail threads)
    const int n    = tid - g*NN;          // node 0..69
    const bool act = (tid < NPAIR);
    const int gl   = act ? g : 0;         // clamp for safe LDS addressing
    const int b    = blk*NB + gl;

    float ann = 0.f;
    float pr[SS];
    #pragma unroll
    for (int s = 0; s < SS; ++s) pr[s] = 0.f;
    if (act) { ann = (float)ann_g[b*NN + n]; pr[0] = ann; }

    #pragma unroll 1
    for (int step = 0; step < STEPS; ++step) {
        // ---- U-build: 30 padded rows, 3 b128 broadcasts each, bias at col 10
        {
            _Float16* uw = &sm.u.s.U[(gl*SS)*USTR + n];
            #pragma unroll
            for (int e = 0; e < EE; ++e)
                #pragma unroll
                for (int s = 0; s < SS; ++s) {
                    const v4f* wr = LW4 + (PWIN/4) + (e*SS + s)*3;
                    const v4f w0 = wr[0], w1 = wr[1], w2 = wr[2];
                    float uv = w2.z
                        + w0.x*pr[0] + w0.y*pr[1] + w0.z*pr[2] + w0.w*pr[3]
                        + w1.x*pr[4] + w1.y*pr[5] + w1.z*pr[6] + w1.w*pr[7]
                        + w2.x*pr[8] + w2.y*pr[9];
                    if (act) uw[s*USTR + e*NN] = (_Float16)uv;
                }
        }
        __syncthreads();   // U complete before B-frag reads

        // ---- MFMA: wave w -> M-tile w, 3 N-tiles, 7 K-tiles
        {
            const int c = lane & 15, q = lane >> 4;
            #pragma unroll
            for (int nt = 0; nt < 3; ++nt) {
                v4f acc = {0.f, 0.f, 0.f, 0.f};
                const _Float16* Ub = &sm.u.s.U[(nt*16 + c)*USTR + q*8];
                #pragma unroll
                for (int kt = 0; kt < 7; ++kt) {
                    v8h bfrag = *(const v8h*)(Ub + kt*32);
                    acc = __builtin_amdgcn_mfma_f32_16x16x32_f16(a_frag[kt], bfrag, acc, 0, 0, 0);
                }
                v4h ch = { (_Float16)acc[0], (_Float16)acc[1],
                           (_Float16)acc[2], (_Float16)acc[3] };
                _Float16* cwp = &sm.u.s.C[(nt*16 + c)*CSTRH + w*16 + q*4];
                *(v4h*)cwp = ch;
            }
        }
        __syncthreads();   // C complete before gate reads

        // ---- gates: weight rows = 5 b128 broadcasts each
        {
            float cat[2*SS];
            const _Float16* cr = &sm.u.s.C[(gl*SS)*CSTRH + n];
            #pragma unroll
            for (int s = 0; s < SS; ++s) cat[s] = (float)cr[s*CSTRH];
            #pragma unroll
            for (int s = 0; s < SS; ++s) cat[SS+s] = pr[s];

            float rp[SS], hh[SS], zz[SS];
            #pragma unroll
            for (int s = 0; s < SS; ++s) {
                const v4f* wr = LW4 + (PWR/4) + s*5;
                const v4f w0=wr[0], w1=wr[1], w2=wr[2], w3=wr[3], w4=wr[4];
                float acc = lw[PBR+s]
                    + w0.x*cat[0]  + w0.y*cat[1]  + w0.z*cat[2]  + w0.w*cat[3]
                    + w1.x*cat[4]  + w1.y*cat[5]  + w1.z*cat[6]  + w1.w*cat[7]
                    + w2.x*cat[8]  + w2.y*cat[9]  + w2.z*cat[10] + w2.w*cat[11]
                    + w3.x*cat[12] + w3.y*cat[13] + w3.z*cat[14] + w3.w*cat[15]
                    + w4.x*cat[16] + w4.y*cat[17] + w4.z*cat[18] + w4.w*cat[19];
                rp[s] = fast_sigmoid(acc) * pr[s];   // r * prop
            }
            #pragma unroll
            for (int s = 0; s < SS; ++s) {
                const v4f* wr = LW4 + (PWZ/4) + s*5;
                const v4f w0=wr[0], w1=wr[1], w2=wr[2], w3=wr[3], w4=wr[4];
                float acc = lw[PBZ+s]
                    + w0.x*cat[0]  + w0.y*cat[1]  + w0.z*cat[2]  + w0.w*cat[3]
                    + w1.x*cat[4]  + w1.y*cat[5]  + w1.z*cat[6]  + w1.w*cat[7]
                    + w2.x*cat[8]  + w2.y*cat[9]  + w2.z*cat[10] + w2.w*cat[11]
                    + w3.x*cat[12] + w3.y*cat[13] + w3.z*cat[14] + w3.w*cat[15]
                    + w4.x*cat[16] + w4.y*cat[17] + w4.z*cat[18] + w4.w*cat[19];
                zz[s] = fast_sigmoid(acc);
            }
            // overwrite upper half of cat with r*prop for the h-gate
            #pragma unroll
            for (int s = 0; s < SS; ++s) cat[SS+s] = rp[s];
            #pragma unroll
            for (int s = 0; s < SS; ++s) {
                const v4f* wr = LW4 + (PWH/4) + s*5;
                const v4f w0=wr[0], w1=wr[1], w2=wr[2], w3=wr[3], w4=wr[4];
                float acc = lw[PBH+s]
                    + w0.x*cat[0]  + w0.y*cat[1]  + w0.z*cat[2]  + w0.w*cat[3]
                    + w1.x*cat[4]  + w1.y*cat[5]  + w1.z*cat[6]  + w1.w*cat[7]
                    + w2.x*cat[8]  + w2.y*cat[9]  + w2.z*cat[10] + w2.w*cat[11]
                    + w3.x*cat[12] + w3.y*cat[13] + w3.z*cat[14] + w3.w*cat[15]
                    + w4.x*cat[16] + w4.y*cat[17] + w4.z*cat[18] + w4.w*cat[19];
                hh[s] = fast_tanh(acc);
            }
            #pragma unroll
            for (int s = 0; s < SS; ++s) pr[s] += zz[s]*(hh[s]-pr[s]);
        }
        __syncthreads();   // gates' C reads done before next step's writes
    }

    // ---- epilogue: rows [Wo1[s][0..9], ann_coef, bo1]
    if (act) {
        float o = lw[PBO2];
        #pragma unroll
        for (int s = 0; s < SS; ++s) {
            const v4f* wr = LW4 + (PWO1/4) + s*3;
            const v4f w0 = wr[0], w1 = wr[1], w2 = wr[2];
            float acc = w2.w + w2.z*ann
                + w0.x*pr[0] + w0.y*pr[1] + w0.z*pr[2] + w0.w*pr[3]
                + w1.x*pr[4] + w1.y*pr[5] + w1.z*pr[6] + w1.w*pr[7]
                + w2.x*pr[8] + w2.y*pr[9];
            o += fast_tanh(acc) * lw[PWO2 + s];
        }
        out_g[b*NN + n] = (T)o;
    }
}

// min-waves=4: 128-VGPR budget (R7-verified no-spill); NOT 5 (rounds to
// 8 waves/EU -> 64-VGPR budget -> spill, R1/R3/R5/R6).
__global__ __launch_bounds__(TPB, 4)
void ggnn_kernel(const void* annv, const void* Av, void* outv)
{
    __shared__ Smem sm;
    if (g_flag)
        run_impl<__hip_bfloat16>(annv, Av, outv, sm);
    else
        run_impl<float>(annv, Av, outv, sm);
}

extern "C" void kernel_launch(void* const* d_in, const int* in_sizes, int n_in,
                              void* d_out, int out_size, void* d_ws, size_t ws_size,
                              hipStream_t stream) {
    (void)in_sizes; (void)n_in; (void)out_size; (void)d_ws; (void)ws_size;
    hipLaunchKernelGGL(prep_kernel, dim3(1), dim3(256), 0, stream,
        d_in[0], d_in[2], d_in[3], d_in[4], d_in[5], d_in[6], d_in[7],
        d_in[8], d_in[9], d_in[10], d_in[11], d_in[12], d_in[13]);
    hipLaunchKernelGGL(ggnn_kernel, dim3(NBLK), dim3(TPB), 0, stream,
        d_in[0], d_in[1], d_out);
}

// Round 9
// 410.965 us; speedup vs baseline: 3.4322x; 1.4927x over previous
//
#include <hip/hip_runtime.h>
#include <hip/hip_bf16.h>

typedef _Float16 v8h __attribute__((ext_vector_type(8)));
typedef _Float16 v4h __attribute__((ext_vector_type(4)));
typedef _Float16 v2h __attribute__((ext_vector_type(2)));
typedef float    v4f __attribute__((ext_vector_type(4)));

#define NTOT  16384
#define NN    70
#define STEPS 5
#define NB    4
#define NPAIR (NB*NN)     // 280 active of 320
#define TPB   320         // 5 waves = 5 node-tiles of 16
#define NBLK  (NTOT/NB)   // 4096
#define CATN  40          // cat_T node stride (halves); 20 dw -> bank-spread, %8=0
#define CATG  3200        // cat_T graph stride (halves) = 80 nodes * 40
#define USTR  232         // U_T col stride (halves); 116 dw -> bank-spread, %8=0
#define AST   224         // Astage row stride (halves); j = e*72 + m (m<70 real)

// epilogue weights (fp32, global; read once via scalar loads)
#define PWO1 0            // 10 rows x 12: [Wo1[s][0..9], Wo1[s][10](ann), bo1[s]]
#define PWO2 120
#define PBO2 130
#define NWP  132

__device__ __align__(16) float    g_w[NWP];
// MFMA weight-fragment images (fp16), built by prep:
//   [0..1023]    P1 B-frags (Wstack):  nt*512 + lane*8 + j
//   [1024..2047] P3 A-frags (Wr, Wz):  mt*512 + lane*8 + j
//   [2048..2559] P3 A-frag  (Wh):      lane*8 + j
__device__ __align__(16) _Float16 g_wf[2560];
__device__ int g_flag;

__device__ __forceinline__ float fast_sigmoid(float x) {
    return __builtin_amdgcn_rcpf(1.0f + __expf(-x));
}
__device__ __forceinline__ float fast_tanh(float x) {
    float ax = fabsf(x);
    float e  = __expf(-2.0f * ax);
    float t  = (1.0f - e) * __builtin_amdgcn_rcpf(1.0f + e);
    return copysignf(t, x);
}

struct __align__(16) Smem {
    union {
        _Float16 Astage[NN*AST];          // 31360 B (adjacency, frag-preload source)
        struct {
            _Float16 U[48*USTR];          // 22272 B: U_T[col=(g,s)][j]
            _Float16 cat[NB*CATG];        // 25600 B: cat_T[g][node][k0..31]
                                          //   k 0..9=a_in, 16..25=prop/rp, 26=1.0
        } s;
    } u;
};
// sizeof = 47872 B -> 3 blocks/CU

// ---- prep: probe dtype; build epilogue weights + MFMA weight-frag images ----
__global__ void prep_kernel(const void* annv,
    const void* winv, const void* binv, const void* wrv, const void* brv,
    const void* wzv, const void* bzv, const void* whv, const void* bhv,
    const void* wo1v, const void* bo1v, const void* wo2v, const void* bo2v)
{
    __shared__ int sflag;
    if (threadIdx.x == 0) {
        const unsigned short* u = (const unsigned short*)annv;
        int good = 0;
        for (int k = 0; k < 128; ++k) {
            unsigned short bb = u[k];
            int ex = (bb >> 7) & 0xFF;
            if (bb == 0 || (ex >= 101 && ex <= 131)) ++good;
        }
        sflag = (good >= 112) ? 1 : 0;
        g_flag = sflag;
    }
    __syncthreads();
    const int f = sflag;
    #define RD(p, i) (f ? (float)((const __hip_bfloat16*)(p))[i] : ((const float*)(p))[i])
    const int tid = threadIdx.x;
    // epilogue block
    for (int idx = tid; idx < 120; idx += blockDim.x) {
        const int s = idx / 12, c = idx - s*12;
        g_w[PWO1 + idx] = (c < 11) ? RD(wo1v, s*11 + c) : RD(bo1v, s);
    }
    for (int idx = tid; idx < 10; idx += blockDim.x) g_w[PWO2 + idx] = RD(wo2v, idx);
    if (tid == 0) { g_w[PBO2] = RD(bo2v, 0); g_w[PBO2+1] = 0.f; }
    // fragment images
    for (int idx = tid; idx < 2560; idx += blockDim.x) {
        float val = 0.f;
        if (idx < 1024) {
            // P1 B-frag: B[k][col], col=(e,s); nonzero k: 16..25 -> Win[e][s][k-16], 26 -> b_in
            const int nt = idx >> 9, rem = idx & 511, lane = rem >> 3, j = rem & 7;
            const int k = ((lane >> 4) << 3) + j, col = nt*16 + (lane & 15);
            if (col < 30) {
                const int e = col / 10, s = col - e*10;
                if (k >= 16 && k < 26) val = RD(winv, e*100 + s*10 + (k-16));
                else if (k == 26)      val = RD(binv, e*10 + s);
            }
        } else if (idx < 2048) {
            // P3 A-frag: A[row=s][k]; k<10 -> W[s][k] (a_in), 16..25 -> W[s][10+k-16] (prop), 26 -> bias
            const int i2 = idx - 1024;
            const int mt = i2 >> 9, rem = i2 & 511, lane = rem >> 3, j = rem & 7;
            const int k = ((lane >> 4) << 3) + j, s = lane & 15;
            if (s < 10) {
                const void* Wv = mt ? wzv : wrv;
                const void* bv = mt ? bzv : brv;
                if (k < 10)                 val = RD(Wv, s*20 + k);
                else if (k >= 16 && k < 26) val = RD(Wv, s*20 + 10 + (k-16));
                else if (k == 26)           val = RD(bv, s);
            }
        } else {
            const int i2 = idx - 2048;
            const int lane = i2 >> 3, j = i2 & 7;
            const int k = ((lane >> 4) << 3) + j, s = lane & 15;
            if (s < 10) {
                if (k < 10)                 val = RD(whv, s*20 + k);
                else if (k >= 16 && k < 26) val = RD(whv, s*20 + 10 + (k-16));
                else if (k == 26)           val = RD(bhv, s);
            }
        }
        g_wf[idx] = (_Float16)val;
    }
    #undef RD
}

template<typename T>
__device__ __forceinline__ void run_impl(const void* annv, const void* Av,
                                         void* outv, Smem& sm)
{
    const T* ann_g = (const T*)annv;
    const T* A_g   = (const T*)Av;
    T* out_g       = (T*)outv;
    const int tid  = threadIdx.x;
    const int blk  = blockIdx.x;
    const int w    = tid >> 6;       // wave id = node-tile id
    const int lane = tid & 63;
    const int q    = lane >> 4;      // quad
    const int c    = lane & 15;
    const float* __restrict__ gw = g_w;

    // ---- stage adjacency: Astage[n][j], j = e*72+m (zeros at m>=70, j>=216)
    for (int idx = tid; idx < NN*AST; idx += TPB) {
        const int n2 = idx / AST, j = idx - n2*AST;
        const int e = j / 72, m = j - e*72;
        float v = 0.f;
        if (j < 216 && m < NN) v = (float)A_g[n2*210 + e*70 + m];
        sm.u.Astage[idx] = (_Float16)v;
    }
    __syncthreads();

    // ---- preload adjacency A-frags (wave w -> nodes w*16..w*16+15)
    v8h a_adj[7];
    {
        const int m  = w*16 + c;
        const int mr = (m < NN) ? m : 0;
        const _Float16* As = &sm.u.Astage[mr*AST + q*8];
        const v8h z8 = {0,0,0,0,0,0,0,0};
        #pragma unroll
        for (int kt = 0; kt < 7; ++kt)
            a_adj[kt] = (m < NN) ? *(const v8h*)(As + kt*32) : z8;
    }
    // ---- preload weight frags (global, coalesced, once)
    const v8h w1f0  = *(const v8h*)&g_wf[        lane*8];
    const v8h w1f1  = *(const v8h*)&g_wf[ 512 +  lane*8];
    const v8h wrf   = *(const v8h*)&g_wf[1024 +  lane*8];
    const v8h wzf   = *(const v8h*)&g_wf[1536 +  lane*8];
    const v8h whf   = *(const v8h*)&g_wf[2048 +  lane*8];
    __syncthreads();   // frag reads done before union overwrite

    // ---- zero U_T + cat_T
    {
        int* z = (int*)&sm.u.s;
        const int ndw = (int)(sizeof(sm.u.s) / 4);
        for (int idx = tid; idx < ndw; idx += TPB) z[idx] = 0;
    }
    __syncthreads();

    // ---- init: thread (g,n) seeds prop[0]=ann and the bias-one at k=26
    const int gth  = tid / NN;          // graph 0..3 (4 = tail)
    const int nth  = tid - gth*NN;
    const bool act = (tid < NPAIR);
    const int gl   = act ? gth : 0;
    const int b    = blk*NB + gl;
    float ann = 0.f;
    if (act) {
        ann = (float)ann_g[b*NN + nth];
        sm.u.s.cat[gl*CATG + nth*CATN + 16] = (_Float16)ann;
        sm.u.s.cat[gl*CATG + nth*CATN + 26] = (_Float16)1.0f;
    }
    __syncthreads();

    const int node  = w*16 + c;          // this lane's node col in MFMA phases
    const int node0 = w*16 + q*4;        // this lane's C-frag row base

    #pragma unroll 1
    for (int step = 0; step < STEPS; ++step) {
        // ---- P1: ins = prop @ Wstack (per graph), weights in frags
        #pragma unroll
        for (int g2 = 0; g2 < NB; ++g2) {
            const v8h af = *(const v8h*)&sm.u.s.cat[g2*CATG + node*CATN + q*8];
            #pragma unroll
            for (int nt = 0; nt < 2; ++nt) {
                v4f acc = {0.f,0.f,0.f,0.f};
                acc = __builtin_amdgcn_mfma_f32_16x16x32_f16(af, nt ? w1f1 : w1f0, acc, 0,0,0);
                const int colw = nt*16 + c;
                if (colw < 30 && node0 <= 68) {
                    const int e = colw / 10, s = colw - e*10;
                    v4h hv = {(_Float16)acc[0],(_Float16)acc[1],(_Float16)acc[2],(_Float16)acc[3]};
                    *(v4h*)&sm.u.s.U[(g2*10 + s)*USTR + e*72 + node0] = hv;
                }
            }
        }
        __syncthreads();   // U_T complete (cross-wave) before P2 reads

        // ---- P2: a_in = A_adj @ U (M=own nodes, N=48 cols, K=224)
        #pragma unroll
        for (int nt = 0; nt < 3; ++nt) {
            v4f acc = {0.f,0.f,0.f,0.f};
            const _Float16* Ub = &sm.u.s.U[(nt*16 + c)*USTR + q*8];
            #pragma unroll
            for (int kt = 0; kt < 7; ++kt) {
                const v8h bf = *(const v8h*)(Ub + kt*32);
                acc = __builtin_amdgcn_mfma_f32_16x16x32_f16(a_adj[kt], bf, acc, 0,0,0);
            }
            const int colc = nt*16 + c;
            if (colc < 40) {
                const int g2 = colc / 10, s = colc - g2*10;
                #pragma unroll
                for (int r = 0; r < 4; ++r) {
                    const int nd = node0 + r;
                    if (nd < NN)
                        sm.u.s.cat[g2*CATG + nd*CATN + s] = (_Float16)acc[r];
                }
            }
        }
        // no barrier: P3 reads only this wave's own nodes (written above)

        // ---- P3: gates via MFMA (A=W-frags, B=cat rows of own nodes)
        float zg[NB][4], pg[NB][4];
        #pragma unroll
        for (int g2 = 0; g2 < NB; ++g2) {
            const v8h bf = *(const v8h*)&sm.u.s.cat[g2*CATG + node*CATN + q*8];
            v4f ar = {0.f,0.f,0.f,0.f}, az = {0.f,0.f,0.f,0.f};
            ar = __builtin_amdgcn_mfma_f32_16x16x32_f16(wrf, bf, ar, 0,0,0);
            az = __builtin_amdgcn_mfma_f32_16x16x32_f16(wzf, bf, az, 0,0,0);
            const v4h pv = *(const v4h*)&sm.u.s.cat[g2*CATG + node*CATN + 16 + q*4];
            _Float16 rp[4];
            #pragma unroll
            for (int i = 0; i < 4; ++i) {
                const float p = (float)pv[i];
                pg[g2][i] = p;
                zg[g2][i] = fast_sigmoid(az[i]);
                rp[i] = (_Float16)(fast_sigmoid(ar[i]) * p);
            }
            if (node < NN) {
                _Float16* wr_ = &sm.u.s.cat[g2*CATG + node*CATN + 16 + q*4];
                if (q < 2)       *(v4h*)wr_ = (v4h){rp[0],rp[1],rp[2],rp[3]};
                else if (q == 2) *(v2h*)wr_ = (v2h){rp[0],rp[1]};
            }
        }
        #pragma unroll
        for (int g2 = 0; g2 < NB; ++g2) {
            const v8h bf = *(const v8h*)&sm.u.s.cat[g2*CATG + node*CATN + q*8];
            v4f ah = {0.f,0.f,0.f,0.f};
            ah = __builtin_amdgcn_mfma_f32_16x16x32_f16(whf, bf, ah, 0,0,0);
            _Float16 pn[4];
            #pragma unroll
            for (int i = 0; i < 4; ++i) {
                const float hh = fast_tanh(ah[i]);
                pn[i] = (_Float16)(pg[g2][i] + zg[g2][i]*(hh - pg[g2][i]));
            }
            if (node < NN) {
                _Float16* wr_ = &sm.u.s.cat[g2*CATG + node*CATN + 16 + q*4];
                if (q < 2)       *(v4h*)wr_ = (v4h){pn[0],pn[1],pn[2],pn[3]};
                else if (q == 2) *(v2h*)wr_ = (v2h){pn[0],pn[1]};
            }
        }
        __syncthreads();   // prior P2 U-reads + new prop complete before next P1
    }

    // ---- epilogue: thread (g,n) reads final prop, computes output
    if (act) {
        const _Float16* pc = &sm.u.s.cat[gl*CATG + nth*CATN + 16];
        const v8h p8 = *(const v8h*)pc;
        const v2h p2 = *(const v2h*)(pc + 8);
        float pr[10];
        #pragma unroll
        for (int i = 0; i < 8; ++i) pr[i] = (float)p8[i];
        pr[8] = (float)p2[0]; pr[9] = (float)p2[1];
        float o = gw[PBO2];
        #pragma unroll
        for (int s = 0; s < 10; ++s) {
            const float* wr_ = &gw[PWO1 + s*12];
            float acc = wr_[11] + wr_[10]*ann;
            #pragma unroll
            for (int d = 0; d < 10; ++d) acc += pr[d]*wr_[d];
            o += fast_tanh(acc) * gw[PWO2 + s];
        }
        out_g[b*NN + nth] = (T)o;
    }
}

// min-waves=4: 128-VGPR budget (R7-verified no-spill); NOT 5 (rounds up to
// 8 waves/EU -> 64-VGPR cap -> spill, seen R1/R3/R5/R6).
__global__ __launch_bounds__(TPB, 4)
void ggnn_kernel(const void* annv, const void* Av, void* outv)
{
    __shared__ Smem sm;
    if (g_flag)
        run_impl<__hip_bfloat16>(annv, Av, outv, sm);
    else
        run_impl<float>(annv, Av, outv, sm);
}

extern "C" void kernel_launch(void* const* d_in, const int* in_sizes, int n_in,
                              void* d_out, int out_size, void* d_ws, size_t ws_size,
                              hipStream_t stream) {
    (void)in_sizes; (void)n_in; (void)out_size; (void)d_ws; (void)ws_size;
    hipLaunchKernelGGL(prep_kernel, dim3(1), dim3(256), 0, stream,
        d_in[0], d_in[2], d_in[3], d_in[4], d_in[5], d_in[6], d_in[7],
        d_in[8], d_in[9], d_in[10], d_in[11], d_in[12], d_in[13]);
    hipLaunchKernelGGL(ggnn_kernel, dim3(NBLK), dim3(TPB), 0, stream,
        d_in[0], d_in[1], d_out);
}

// Round 10
// 345.071 us; speedup vs baseline: 4.0877x; 1.1910x over previous
//
#include <hip/hip_runtime.h>
#include <hip/hip_bf16.h>

typedef _Float16 v8h __attribute__((ext_vector_type(8)));
typedef _Float16 v4h __attribute__((ext_vector_type(4)));
typedef _Float16 v2h __attribute__((ext_vector_type(2)));
typedef float    v4f __attribute__((ext_vector_type(4)));

#define NTOT  16384
#define NN    70
#define STEPS 5
#define NB    3
#define NPAIR (NB*NN)               // 210 active of 320
#define TPB   320                   // 5 waves = 5 node-tiles of 16
#define NBLK  ((NTOT + NB - 1)/NB)  // 5462
#define CATN  40                    // cat node stride (halves), 16B-mult
#define CATG  3208                  // cat graph stride: 1604 dw = 4 mod 32 (scatter spread)
#define USTR  232                   // U col stride (halves): 116 dw = 20 mod 32 (2-way max)
#define UCOLS 30                    // (g,s) cols
#define UBUF  (UCOLS*USTR)          // 6960 halves per buffer

// epilogue weights (fp32, global scalar loads)
#define PWO1 0                      // 10 rows x 12: [Wo1[s][0..9], ann_coef, bo1[s]]
#define PWO2 120
#define PBO2 130
#define NWP  132

// fp16 fragment images (built by prep):
//  [0..1023]     P1 B-frags Wstack, 2 tiles:  nt*512 + lane*8 + j
//  [1024..2047]  P3 A-frags Wr | Wz:          mt*512 + lane*8 + j
//  [2048..2559]  P3 A-frag  Wh:               lane*8 + j
//  [2560..20479] adjacency A-frags:           2560 + (w*7+kt)*512 + lane*8 + j
#define OFR  1024
#define OFZ  1536
#define OFH  2048
#define OFA  2560
#define NWF  20480

__device__ __align__(16) float    g_w[NWP];
__device__ __align__(16) _Float16 g_wf[NWF];
__device__ int g_flag;

__device__ __forceinline__ float fast_sigmoid(float x) {
    return __builtin_amdgcn_rcpf(1.0f + __expf(-x));
}
__device__ __forceinline__ float fast_tanh(float x) {
    float ax = fabsf(x);
    float e  = __expf(-2.0f * ax);
    float t  = (1.0f - e) * __builtin_amdgcn_rcpf(1.0f + e);
    return copysignf(t, x);
}

struct __align__(16) Smem {
    _Float16 U[2*UBUF];      // 27840 B: double-buffered U_T[col=(g,s)][k=e*72+m]
    _Float16 cat[NB*CATG];   // 19248 B: cat_T[g][node][k]; k0..9=a_in, 16..25=prop, 26=1
};
// sizeof = 47088 B -> 3 blocks/CU

// ---- prep: probe dtype; build epilogue weights + all fp16 fragment images ----
__global__ void prep_kernel(const void* annv, const void* Av,
    const void* winv, const void* binv, const void* wrv, const void* brv,
    const void* wzv, const void* bzv, const void* whv, const void* bhv,
    const void* wo1v, const void* bo1v, const void* wo2v, const void* bo2v)
{
    __shared__ int sflag;
    if (threadIdx.x == 0) {
        const unsigned short* u = (const unsigned short*)annv;
        int good = 0;
        for (int k = 0; k < 128; ++k) {
            unsigned short bb = u[k];
            int ex = (bb >> 7) & 0xFF;
            if (bb == 0 || (ex >= 101 && ex <= 131)) ++good;
        }
        sflag = (good >= 112) ? 1 : 0;
        g_flag = sflag;
    }
    __syncthreads();
    const int f = sflag;
    #define RD(p, i) (f ? (float)((const __hip_bfloat16*)(p))[i] : ((const float*)(p))[i])
    const int tid = threadIdx.x;
    // epilogue block
    for (int idx = tid; idx < 120; idx += blockDim.x) {
        const int s = idx / 12, c = idx - s*12;
        g_w[PWO1 + idx] = (c < 11) ? RD(wo1v, s*11 + c) : RD(bo1v, s);
    }
    for (int idx = tid; idx < 10; idx += blockDim.x) g_w[PWO2 + idx] = RD(wo2v, idx);
    if (tid == 0) { g_w[PBO2] = RD(bo2v, 0); g_w[PBO2+1] = 0.f; }
    // fragment images
    for (int idx = tid; idx < NWF; idx += blockDim.x) {
        float val = 0.f;
        if (idx < OFR) {
            // P1 B-frag: B[k][col=(e,s)]; k 16..25 -> Win[e][s][k-16], k 26 -> b_in
            const int nt = idx >> 9, rem = idx & 511, lane = rem >> 3, j = rem & 7;
            const int k = ((lane >> 4) << 3) + j, col = nt*16 + (lane & 15);
            if (col < 30) {
                const int e = col / 10, s = col - e*10;
                if (k >= 16 && k < 26) val = RD(winv, e*100 + s*10 + (k-16));
                else if (k == 26)      val = RD(binv, e*10 + s);
            }
        } else if (idx < OFH) {
            // P3 A-frags Wr/Wz: A[row=s][k]; k<10 -> W[s][k], 16..25 -> W[s][10+..], 26 -> bias
            const int i2 = idx - OFR;
            const int mt = i2 >> 9, rem = i2 & 511, lane = rem >> 3, j = rem & 7;
            const int k = ((lane >> 4) << 3) + j, s = lane & 15;
            if (s < 10) {
                const void* Wv = mt ? wzv : wrv;
                const void* bv = mt ? bzv : brv;
                if (k < 10)                 val = RD(Wv, s*20 + k);
                else if (k >= 16 && k < 26) val = RD(Wv, s*20 + 10 + (k-16));
                else if (k == 26)           val = RD(bv, s);
            }
        } else if (idx < OFA) {
            const int i2 = idx - OFH;
            const int lane = i2 >> 3, j = i2 & 7;
            const int k = ((lane >> 4) << 3) + j, s = lane & 15;
            if (s < 10) {
                if (k < 10)                 val = RD(whv, s*20 + k);
                else if (k >= 16 && k < 26) val = RD(whv, s*20 + 10 + (k-16));
                else if (k == 26)           val = RD(bhv, s);
            }
        } else {
            // adjacency A-frag: A[m=node][k=e*72+mm]; zero at pads
            const int i2 = idx - OFA;
            const int w = i2 / 3584, rem = i2 - w*3584;
            const int kt = rem >> 9, r2 = rem & 511, lane = r2 >> 3, j = r2 & 7;
            const int m = w*16 + (lane & 15);
            const int k = kt*32 + ((lane >> 4) << 3) + j;
            const int e = k / 72, mm = k - e*72;
            if (m < NN && e < 3 && mm < NN) val = RD(Av, m*210 + e*70 + mm);
        }
        g_wf[idx] = (_Float16)val;
    }
    #undef RD
}

template<typename T>
__device__ __forceinline__ void run_impl(const void* annv, void* outv, Smem& sm)
{
    const T* ann_g = (const T*)annv;
    T* out_g       = (T*)outv;
    const int tid  = threadIdx.x;
    const int blk  = blockIdx.x;
    const int w    = tid >> 6;
    const int lane = tid & 63;
    const int q    = lane >> 4;
    const int c    = lane & 15;
    const int node  = w*16 + c;      // lane's node col in MFMA phases
    const int node0 = w*16 + q*4;    // lane's C-frag row base
    const float* __restrict__ gw = g_w;

    // ---- preload all fragments from global (coalesced, once per block)
    const v8h w1f0 = *(const v8h*)&g_wf[       lane*8];
    const v8h w1f1 = *(const v8h*)&g_wf[512  + lane*8];
    const v8h wrf  = *(const v8h*)&g_wf[OFR  + lane*8];
    const v8h wzf  = *(const v8h*)&g_wf[OFZ  + lane*8];
    const v8h whf  = *(const v8h*)&g_wf[OFH  + lane*8];
    v8h a_adj[7];
    #pragma unroll
    for (int kt = 0; kt < 7; ++kt)
        a_adj[kt] = *(const v8h*)&g_wf[OFA + (w*7 + kt)*512 + lane*8];

    // ---- zero U (both bufs) + cat
    {
        int* z = (int*)&sm;
        const int ndw = (int)(sizeof(Smem) / 4);
        for (int idx = tid; idx < ndw; idx += TPB) z[idx] = 0;
    }
    __syncthreads();

    // ---- init: thread (g,n) seeds prop[0]=ann, bias-one at k=26
    const int gth  = tid / NN;
    const int nth  = tid - gth*NN;
    const int b    = blk*NB + gth;
    const bool act = (tid < NPAIR) && (b < NTOT);
    float ann = 0.f;
    if (act) {
        ann = (float)ann_g[b*NN + nth];
        sm.cat[gth*CATG + nth*CATN + 16] = (_Float16)ann;
        sm.cat[gth*CATG + nth*CATN + 26] = (_Float16)1.0f;
    }
    __syncthreads();

    // ---- P1 as a lambda-ish macro: ins(prop) -> U[buf]
    #define PHASE1(BUF) do {                                                     \
        _Float16* Ub_ = &sm.U[(BUF)*UBUF];                                       \
        _Pragma("unroll")                                                        \
        for (int g2 = 0; g2 < NB; ++g2) {                                        \
            const v8h af = *(const v8h*)&sm.cat[g2*CATG + node*CATN + q*8];      \
            _Pragma("unroll")                                                    \
            for (int nt = 0; nt < 2; ++nt) {                                     \
                v4f acc = {0.f,0.f,0.f,0.f};                                     \
                acc = __builtin_amdgcn_mfma_f32_16x16x32_f16(                    \
                        af, nt ? w1f1 : w1f0, acc, 0,0,0);                       \
                const int colw = nt*16 + c;                                      \
                if (colw < 30 && node0 <= 68) {                                  \
                    const int e = colw / 10, s = colw - e*10;                    \
                    v4h hv = {(_Float16)acc[0],(_Float16)acc[1],                 \
                              (_Float16)acc[2],(_Float16)acc[3]};                \
                    *(v4h*)&Ub_[(g2*10 + s)*USTR + e*72 + node0] = hv;           \
                }                                                                \
            }                                                                    \
        }                                                                        \
    } while(0)

    PHASE1(0);   // from initial prop

    #pragma unroll 1
    for (int step = 0; step < STEPS; ++step) {
        const int buf = step & 1;
        __syncthreads();   // U[buf] complete; prior readers of U[buf^1] done

        // ---- P2: a_in = A_adj @ U[buf]  (M=own nodes, N=30 cols, K=224)
        {
            const _Float16* Ub = &sm.U[buf*UBUF];
            #pragma unroll
            for (int nt = 0; nt < 2; ++nt) {
                v4f acc = {0.f,0.f,0.f,0.f};
                const _Float16* Up = &Ub[(nt*16 + c)*USTR + q*8];
                #pragma unroll
                for (int kt = 0; kt < 7; ++kt) {
                    const v8h bf = *(const v8h*)(Up + kt*32);
                    acc = __builtin_amdgcn_mfma_f32_16x16x32_f16(a_adj[kt], bf, acc, 0,0,0);
                }
                const int colc = nt*16 + c;
                if (colc < 30) {
                    const int g2 = colc / 10, s = colc - g2*10;
                    #pragma unroll
                    for (int r = 0; r < 4; ++r) {
                        const int nd = node0 + r;
                        if (nd < NN)
                            sm.cat[g2*CATG + nd*CATN + s] = (_Float16)acc[r];
                    }
                }
            }
        }

        // ---- P3: gates (same-wave: own nodes' cat rows)
        {
            float zg[NB][4], pg[NB][4];
            #pragma unroll
            for (int g2 = 0; g2 < NB; ++g2) {
                const v8h bf = *(const v8h*)&sm.cat[g2*CATG + node*CATN + q*8];
                v4f ar = {0.f,0.f,0.f,0.f}, az = {0.f,0.f,0.f,0.f};
                ar = __builtin_amdgcn_mfma_f32_16x16x32_f16(wrf, bf, ar, 0,0,0);
                az = __builtin_amdgcn_mfma_f32_16x16x32_f16(wzf, bf, az, 0,0,0);
                const v4h pv = *(const v4h*)&sm.cat[g2*CATG + node*CATN + 16 + q*4];
                _Float16 rp[4];
                #pragma unroll
                for (int i = 0; i < 4; ++i) {
                    const float p = (float)pv[i];
                    pg[g2][i] = p;
                    zg[g2][i] = fast_sigmoid(az[i]);
                    rp[i] = (_Float16)(fast_sigmoid(ar[i]) * p);
                }
                if (node < NN) {
                    _Float16* wr_ = &sm.cat[g2*CATG + node*CATN + 16 + q*4];
                    if (q < 2)       *(v4h*)wr_ = (v4h){rp[0],rp[1],rp[2],rp[3]};
                    else if (q == 2) *(v2h*)wr_ = (v2h){rp[0],rp[1]};
                }
            }
            #pragma unroll
            for (int g2 = 0; g2 < NB; ++g2) {
                const v8h bf = *(const v8h*)&sm.cat[g2*CATG + node*CATN + q*8];
                v4f ah = {0.f,0.f,0.f,0.f};
                ah = __builtin_amdgcn_mfma_f32_16x16x32_f16(whf, bf, ah, 0,0,0);
                _Float16 pn[4];
                #pragma unroll
                for (int i = 0; i < 4; ++i) {
                    const float hh = fast_tanh(ah[i]);
                    pn[i] = (_Float16)(pg[g2][i] + zg[g2][i]*(hh - pg[g2][i]));
                }
                if (node < NN) {
                    _Float16* wr_ = &sm.cat[g2*CATG + node*CATN + 16 + q*4];
                    if (q < 2)       *(v4h*)wr_ = (v4h){pn[0],pn[1],pn[2],pn[3]};
                    else if (q == 2) *(v2h*)wr_ = (v2h){pn[0],pn[1]};
                }
            }
        }

        // ---- P1 for next step (same-wave deps only; writes the OTHER U buffer)
        if (step < STEPS-1) PHASE1(buf ^ 1);
    }
    #undef PHASE1

    __syncthreads();   // final prop visible across waves for (g,n)-mapped epilogue

    // ---- epilogue
    if (act) {
        const _Float16* pc = &sm.cat[gth*CATG + nth*CATN + 16];
        const v8h p8 = *(const v8h*)pc;
        const v2h p2 = *(const v2h*)(pc + 8);
        float pr[10];
        #pragma unroll
        for (int i = 0; i < 8; ++i) pr[i] = (float)p8[i];
        pr[8] = (float)p2[0]; pr[9] = (float)p2[1];
        float o = gw[PBO2];
        #pragma unroll
        for (int s = 0; s < 10; ++s) {
            const float* wr_ = &gw[PWO1 + s*12];
            float acc = wr_[11] + wr_[10]*ann;
            #pragma unroll
            for (int d = 0; d < 10; ++d) acc += pr[d]*wr_[d];
            o += fast_tanh(acc) * gw[PWO2 + s];
        }
        out_g[b*NN + nth] = (T)o;
    }
}

// min-waves=4: 128-VGPR budget (R7-verified no-spill); NOT 5 (rounds up to
// 8 waves/EU -> 64-VGPR cap -> spill, seen R1/R3/R5/R6).
__global__ __launch_bounds__(TPB, 4)
void ggnn_kernel(const void* annv, void* outv)
{
    __shared__ Smem sm;
    if (g_flag)
        run_impl<__hip_bfloat16>(annv, outv, sm);
    else
        run_impl<float>(annv, outv, sm);
}

extern "C" void kernel_launch(void* const* d_in, const int* in_sizes, int n_in,
                              void* d_out, int out_size, void* d_ws, size_t ws_size,
                              hipStream_t stream) {
    (void)in_sizes; (void)n_in; (void)out_size; (void)d_ws; (void)ws_size;
    hipLaunchKernelGGL(prep_kernel, dim3(1), dim3(256), 0, stream,
        d_in[0], d_in[1], d_in[2], d_in[3], d_in[4], d_in[5], d_in[6],
        d_in[7], d_in[8], d_in[9], d_in[10], d_in[11], d_in[12], d_in[13]);
    hipLaunchKernelGGL(ggnn_kernel, dim3(NBLK), dim3(TPB), 0, stream,
        d_in[0], d_out);
}